// Round 2
// baseline (253.819 us; speedup 1.0000x reference)
//
#include <hip/hip_runtime.h>
#include <hip/hip_bf16.h>
#include <math.h>

// Problem sizes (fixed by reference): B=256, M=64, N=32, D=128, T=64, L=128
#define B_ 256
#define M_ 64
#define N_ 32
#define D_ 128
#define T_ 64
#define L_ 128

typedef __attribute__((ext_vector_type(8))) short short8;   // 8 bf16 = 4 VGPRs (MFMA A/B frag)
typedef __attribute__((ext_vector_type(4))) float floatx4;  // MFMA C/D frag

__device__ __forceinline__ unsigned short f2bf(float f) {
  unsigned int u = __float_as_uint(f);
  unsigned int r = (u + 0x7fffu + ((u >> 16) & 1u)) >> 16;  // RNE
  return (unsigned short)r;
}
__device__ __forceinline__ float bf2f(unsigned short s) {
  return __uint_as_float(((unsigned int)s) << 16);
}

// ---------------------------------------------------------------------------
// K0: cast x -> bf16 (layout [B][M][D]) and normalize routing_leaves rows ->
// bf16 LHn (layout [L][T]).
// ---------------------------------------------------------------------------
__global__ __launch_bounds__(256) void k_prep(const float* __restrict__ x,
                                              const float* __restrict__ leaves,
                                              unsigned short* __restrict__ xb,
                                              unsigned short* __restrict__ lhn) {
  if (blockIdx.x < 2048) {
    size_t e = ((size_t)blockIdx.x * 256 + threadIdx.x) * 4;
    float4 v = *(const float4*)(x + e);
    ushort4 o;
    o.x = f2bf(v.x); o.y = f2bf(v.y); o.z = f2bf(v.z); o.w = f2bf(v.w);
    *(ushort4*)(xb + e) = o;
  } else {
    int l = threadIdx.x;
    if (l < L_) {
      const float* r = leaves + l * T_;
      float ss = 0.f;
      for (int i = 0; i < T_; ++i) ss = fmaf(r[i], r[i], ss);
      float inv = 1.0f / fmaxf(sqrtf(ss), 1e-12f);
      unsigned short* o = lhn + l * T_;
      for (int i = 0; i < T_; ++i) o[i] = f2bf(r[i] * inv);
    }
  }
}

// ---------------------------------------------------------------------------
// K1: exact entmax-1.5 over the D axis of route_weights [M,N,D,T].
// Two threads per (m,n,t) vector; each holds 64 of the 128 elements in VGPRs.
// tau* is the root of f(tau)=sum(max(x-tau,0)^2)-1 on [-1,0]: 16 bisections
// then one exact solve on the stabilized support (same fixed point as the
// reference sort algorithm; residual error ~1e-8 << bf16).
// Output written TRANSPOSED as Wq2[m][n][t][d] bf16 so the priors-GEMM
// B-fragments are contiguous 16B loads.
// ---------------------------------------------------------------------------
__global__ __launch_bounds__(256) void k_entmax(const float* __restrict__ rw,
                                                unsigned short* __restrict__ wq2) {
  const int tid = threadIdx.x;
  const int gv = blockIdx.x * 128 + (tid >> 1);  // vector id = (m*N+n)*T + t
  const int h = tid & 1;
  const int mn = gv >> 6;
  const int t = gv & 63;
  const float* base = rw + ((size_t)mn * D_ + h * 64) * T_ + t;
  float x[64];
#pragma unroll
  for (int i = 0; i < 64; ++i) x[i] = base[(size_t)i * T_];  // coalesced: lanes = consecutive t
  float mx = x[0];
#pragma unroll
  for (int i = 1; i < 64; ++i) mx = fmaxf(mx, x[i]);
  mx = fmaxf(mx, __shfl_xor(mx, 1));
#pragma unroll
  for (int i = 0; i < 64; ++i) x[i] = (x[i] - mx) * 0.5f;  // x/2 - max(x/2)

  float lo = -1.0f, hi = 0.0f;  // f(-1)>=1 (max elem alone), f(0)=0
  for (int it = 0; it < 16; ++it) {
    float tau = 0.5f * (lo + hi);
    float f = 0.0f;
#pragma unroll
    for (int i = 0; i < 64; ++i) {
      float u = fmaxf(x[i] - tau, 0.0f);
      f = fmaf(u, u, f);
    }
    f += __shfl_xor(f, 1);
    if (f >= 1.0f) lo = tau; else hi = tau;
  }
  float tau0 = 0.5f * (lo + hi);
  // exact solve on support {x > tau0}: k*tau^2 - 2*s1*tau + (s2-1) = 0
  float cnt = 0.f, s1 = 0.f, s2 = 0.f;
#pragma unroll
  for (int i = 0; i < 64; ++i) {
    bool in = x[i] > tau0;
    float xv = in ? x[i] : 0.0f;
    cnt += in ? 1.0f : 0.0f;
    s1 += xv;
    s2 = fmaf(xv, xv, s2);
  }
  cnt += __shfl_xor(cnt, 1);
  s1 += __shfl_xor(s1, 1);
  s2 += __shfl_xor(s2, 1);
  float mean = s1 / cnt;
  float ss = s2 - mean * s1;            // == k*(meansq - mean^2)
  float delta = (1.0f - ss) / cnt;
  float tau = mean - sqrtf(fmaxf(delta, 0.0f));

  unsigned short pv[64];
#pragma unroll
  for (int i = 0; i < 64; ++i) {
    float u = fmaxf(x[i] - tau, 0.0f);
    pv[i] = f2bf(u * u);
  }
  // contiguous 128B store per thread at Wq2[(m,n,t)][h*64 ...]
  uint4* o = (uint4*)(wq2 + (size_t)gv * D_ + h * 64);
#pragma unroll
  for (int j = 0; j < 8; ++j) {
    uint4 w;
    w.x = (unsigned)pv[8 * j + 0] | ((unsigned)pv[8 * j + 1] << 16);
    w.y = (unsigned)pv[8 * j + 2] | ((unsigned)pv[8 * j + 3] << 16);
    w.z = (unsigned)pv[8 * j + 4] | ((unsigned)pv[8 * j + 5] << 16);
    w.w = (unsigned)pv[8 * j + 6] | ((unsigned)pv[8 * j + 7] << 16);
    o[j] = w;
  }
}

// ---------------------------------------------------------------------------
// K2: priors[b,m,n,t] = sum_d x[b,m,d] * W[m,n,d,t]  (per-m GEMM, K=128)
// Block = (n, b-tile of 64, m); C tile 64x64; 4 waves x (16 rows x 64 cols);
// mfma_f32_16x16x32_bf16, 16 MFMA/wave. B tile (64 t-rows x 128 d) staged in
// LDS with row stride 136 shorts (128 data + 8 pad; 272B = 17x16B keeps
// uint4 alignment).  [R1 fix: stride was 72 — rows overlapped, tile garbage.]
// Output bf16, layout [b][n][m][t] for K3's contiguous slab read.
// ---------------------------------------------------------------------------
#define BS_STRIDE 136
__global__ __launch_bounds__(256) void k_priors(const unsigned short* __restrict__ xb,
                                                const unsigned short* __restrict__ wq2,
                                                unsigned short* __restrict__ priors) {
  const int n = blockIdx.x, bt = blockIdx.y, m = blockIdx.z;
  const int tid = threadIdx.x;
  const int wid = tid >> 6, lane = tid & 63;
  const int row16 = lane & 15, quad = lane >> 4;
  __shared__ unsigned short Bs[64 * BS_STRIDE];

  const unsigned short* bsrc = wq2 + ((size_t)(m * N_ + n) * T_) * D_;  // 64x128 contiguous
  {
    int tr = tid >> 4;  // 16 rows per pass
    int c = tid & 15;   // 16B chunk within a 256B row
#pragma unroll
    for (int p = 0; p < 4; ++p) {
      int row = p * 16 + tr;
      uint4 v = *(const uint4*)(bsrc + row * D_ + c * 8);
      *(uint4*)&Bs[row * BS_STRIDE + c * 8] = v;
    }
  }
  __syncthreads();

  const int brow = bt * 64 + wid * 16 + row16;
  const unsigned short* aptr = xb + ((size_t)brow * M_ + m) * D_ + quad * 8;
  short8 afr[4];
#pragma unroll
  for (int ks = 0; ks < 4; ++ks) afr[ks] = *(const short8*)(aptr + ks * 32);

  floatx4 acc[4];
#pragma unroll
  for (int cf = 0; cf < 4; ++cf) acc[cf] = (floatx4){0.f, 0.f, 0.f, 0.f};

#pragma unroll
  for (int cf = 0; cf < 4; ++cf) {
#pragma unroll
    for (int ks = 0; ks < 4; ++ks) {
      short8 bfr = *(const short8*)&Bs[(cf * 16 + row16) * BS_STRIDE + ks * 32 + quad * 8];
      acc[cf] = __builtin_amdgcn_mfma_f32_16x16x32_bf16(afr[ks], bfr, acc[cf], 0, 0, 0);
    }
  }

#pragma unroll
  for (int cf = 0; cf < 4; ++cf) {
    int tcol = cf * 16 + row16;
#pragma unroll
    for (int r = 0; r < 4; ++r) {
      int b = bt * 64 + wid * 16 + quad * 4 + r;
      priors[(((size_t)b * N_ + n) * M_ + m) * T_ + tcol] = f2bf(acc[cf][r]);
    }
  }
}

// ---------------------------------------------------------------------------
// K3: one block per (b,n). votes = sigmoid(P @ LHn^T) [64x128] via MFMA,
// then mean-over-m, dis, relu(thread^2 - dis), softmax over m, weighted sum
// of priors, LayerNorm over T. All m are block-local.
// ---------------------------------------------------------------------------
__global__ __launch_bounds__(256) void k_route(const unsigned short* __restrict__ priors,
                                               const unsigned short* __restrict__ lhn,
                                               const float* __restrict__ thr,
                                               const float* __restrict__ gamma,
                                               const float* __restrict__ beta,
                                               float* __restrict__ out) {
  const int n = blockIdx.x, b = blockIdx.y;
  const int tid = threadIdx.x;
  const int wid = tid >> 6, lane = tid & 63;
  const int row16 = lane & 15, quad = lane >> 4;

  __shared__ unsigned short Ps[64 * 72];  // P [m][t] bf16: 64 data + 8 pad
  __shared__ float V[64 * 129];           // votes [m][l] fp32, pad 129 (else 64-way conflict in dis pass)
  __shared__ float mc[128];
  __shared__ float prob[64];

  const unsigned short* psrc = priors + ((size_t)(b * N_ + n) * M_) * T_;  // 8KB contiguous
  {
    int mm = tid >> 2, c = tid & 3;
    uint4 v0 = *(const uint4*)(psrc + mm * T_ + c * 16);
    uint4 v1 = *(const uint4*)(psrc + mm * T_ + c * 16 + 8);
    *(uint4*)&Ps[mm * 72 + c * 16] = v0;
    *(uint4*)&Ps[mm * 72 + c * 16 + 8] = v1;
  }
  __syncthreads();

  short8 afr[2];
#pragma unroll
  for (int ks = 0; ks < 2; ++ks)
    afr[ks] = *(const short8*)&Ps[(wid * 16 + row16) * 72 + ks * 32 + quad * 8];

  floatx4 acc[8];
#pragma unroll
  for (int cf = 0; cf < 8; ++cf) acc[cf] = (floatx4){0.f, 0.f, 0.f, 0.f};

#pragma unroll
  for (int cf = 0; cf < 8; ++cf) {
#pragma unroll
    for (int ks = 0; ks < 2; ++ks) {
      short8 bfr = *(const short8*)(lhn + (cf * 16 + row16) * T_ + ks * 32 + quad * 8);
      acc[cf] = __builtin_amdgcn_mfma_f32_16x16x32_bf16(afr[ks], bfr, acc[cf], 0, 0, 0);
    }
  }

#pragma unroll
  for (int cf = 0; cf < 8; ++cf) {
    int l = cf * 16 + row16;
#pragma unroll
    for (int r = 0; r < 4; ++r) {
      int mr = wid * 16 + quad * 4 + r;
      float z = acc[cf][r];
      V[mr * 129 + l] = 1.0f / (1.0f + __expf(-z));
    }
  }
  __syncthreads();

  if (tid < 128) {  // column means over m (bank = (mm+tid)%32 -> conflict-free)
    float s = 0.f;
    for (int mm = 0; mm < 64; ++mm) s += V[mm * 129 + tid];
    mc[tid] = s * (1.0f / 64.0f);
  }
  __syncthreads();

  if (tid < 64) {  // dis + weight + softmax over m (wave 0)
    float d = 0.f;
    for (int l = 0; l < 128; ++l) {
      float df = V[tid * 129 + l] - mc[l];
      d = fmaf(df, df, d);
    }
    d *= (1.0f / 128.0f);
    float th = thr[tid * N_ + n];
    float w = fmaxf(th * th - d, 0.0f);
    float mxw = w;
    for (int off = 32; off; off >>= 1) mxw = fmaxf(mxw, __shfl_xor(mxw, off));
    float e = __expf(w - mxw);
    float s = e;
    for (int off = 32; off; off >>= 1) s += __shfl_xor(s, off);
    prob[tid] = e / s;
  }
  __syncthreads();

  if (tid < 64) {  // next_caps[t] + LayerNorm over T (wave 0, t = tid)
    float s = 0.f;
    for (int mm = 0; mm < 64; ++mm) s = fmaf(prob[mm], bf2f(Ps[mm * 72 + tid]), s);
    float mu = s;
    for (int off = 32; off; off >>= 1) mu += __shfl_xor(mu, off);
    mu *= (1.0f / 64.0f);
    float df = s - mu;
    float var = df * df;
    for (int off = 32; off; off >>= 1) var += __shfl_xor(var, off);
    var *= (1.0f / 64.0f);
    float o = df * rsqrtf(var + 1e-5f) * gamma[tid] + beta[tid];
    out[((size_t)b * N_ + n) * T_ + tid] = o;
  }
}

// ---------------------------------------------------------------------------
// Workspace layout (bytes):
//   Wq2    [M][N][T][D] bf16 : off 0,           33,554,432
//   priors [B][N][M][T] bf16 : off 33,554,432,  67,108,864
//   xb     [B][M][D]    bf16 : off 100,663,296,  4,194,304
//   LHn    [L][T]       bf16 : off 104,857,600,     16,384
// total ~100 MB
// ---------------------------------------------------------------------------
extern "C" void kernel_launch(void* const* d_in, const int* in_sizes, int n_in,
                              void* d_out, int out_size, void* d_ws, size_t ws_size,
                              hipStream_t stream) {
  const float* x = (const float*)d_in[0];
  const float* rw = (const float*)d_in[1];
  const float* thr = (const float*)d_in[2];
  const float* leaves = (const float*)d_in[3];
  const float* gamma = (const float*)d_in[4];
  const float* beta = (const float*)d_in[5];
  float* out = (float*)d_out;

  char* ws = (char*)d_ws;
  unsigned short* wq2 = (unsigned short*)(ws);
  unsigned short* priors = (unsigned short*)(ws + 33554432);
  unsigned short* xb = (unsigned short*)(ws + 33554432 + 67108864);
  unsigned short* lhn = (unsigned short*)(ws + 33554432 + 67108864 + 4194304);

  hipLaunchKernelGGL(k_prep, dim3(2049), dim3(256), 0, stream, x, leaves, xb, lhn);
  hipLaunchKernelGGL(k_entmax, dim3(1024), dim3(256), 0, stream, rw, wq2);
  hipLaunchKernelGGL(k_priors, dim3(32, 4, 64), dim3(256), 0, stream, xb, wq2, priors);
  hipLaunchKernelGGL(k_route, dim3(32, 256), dim3(256), 0, stream, priors, lhn, thr, gamma, beta, out);
}

// Round 3
// 227.909 us; speedup vs baseline: 1.1137x; 1.1137x over previous
//
#include <hip/hip_runtime.h>
#include <hip/hip_bf16.h>
#include <math.h>

// Problem sizes (fixed by reference): B=256, M=64, N=32, D=128, T=64, L=128
#define B_ 256
#define M_ 64
#define N_ 32
#define D_ 128
#define T_ 64
#define L_ 128

typedef __attribute__((ext_vector_type(8))) short short8;   // 8 bf16 = 4 VGPRs (MFMA A/B frag)
typedef __attribute__((ext_vector_type(4))) float floatx4;  // MFMA C/D frag

__device__ __forceinline__ unsigned short f2bf(float f) {
  unsigned int u = __float_as_uint(f);
  unsigned int r = (u + 0x7fffu + ((u >> 16) & 1u)) >> 16;  // RNE
  return (unsigned short)r;
}
__device__ __forceinline__ float bf2f(unsigned short s) {
  return __uint_as_float(((unsigned int)s) << 16);
}

// ---------------------------------------------------------------------------
// K0: cast x -> bf16 (layout [B][M][D]) and normalize routing_leaves rows ->
// bf16 LHn (layout [L][T]).
// ---------------------------------------------------------------------------
__global__ __launch_bounds__(256) void k_prep(const float* __restrict__ x,
                                              const float* __restrict__ leaves,
                                              unsigned short* __restrict__ xb,
                                              unsigned short* __restrict__ lhn) {
  if (blockIdx.x < 2048) {
    size_t e = ((size_t)blockIdx.x * 256 + threadIdx.x) * 4;
    float4 v = *(const float4*)(x + e);
    ushort4 o;
    o.x = f2bf(v.x); o.y = f2bf(v.y); o.z = f2bf(v.z); o.w = f2bf(v.w);
    *(ushort4*)(xb + e) = o;
  } else {
    int l = threadIdx.x;
    if (l < L_) {
      const float* r = leaves + l * T_;
      float ss = 0.f;
      for (int i = 0; i < T_; ++i) ss = fmaf(r[i], r[i], ss);
      float inv = 1.0f / fmaxf(sqrtf(ss), 1e-12f);
      unsigned short* o = lhn + l * T_;
      for (int i = 0; i < T_; ++i) o[i] = f2bf(r[i] * inv);
    }
  }
}

// ---------------------------------------------------------------------------
// K1: exact entmax-1.5 over the D axis of route_weights [M,N,D,T].
// Two threads per (m,n,t) vector; 12 bisections bracket tau*, then one exact
// quadratic solve on the stabilized support (same fixed point as the
// reference sort algorithm; boundary misclassification margin 2^-12
// contributes O(margin^2) ~ 1e-7 << bf16 resolution).
// Output written TRANSPOSED as Wq2[m][n][t][d] bf16 so the priors-GEMM
// B-fragments are contiguous 16B loads.
// ---------------------------------------------------------------------------
__global__ __launch_bounds__(256) void k_entmax(const float* __restrict__ rw,
                                                unsigned short* __restrict__ wq2) {
  const int tid = threadIdx.x;
  const int gv = blockIdx.x * 128 + (tid >> 1);  // vector id = (m*N+n)*T + t
  const int h = tid & 1;
  const int mn = gv >> 6;
  const int t = gv & 63;
  const float* base = rw + ((size_t)mn * D_ + h * 64) * T_ + t;
  float x[64];
#pragma unroll
  for (int i = 0; i < 64; ++i) x[i] = base[(size_t)i * T_];  // coalesced: lanes = consecutive t
  float mx = x[0];
#pragma unroll
  for (int i = 1; i < 64; ++i) mx = fmaxf(mx, x[i]);
  mx = fmaxf(mx, __shfl_xor(mx, 1));
#pragma unroll
  for (int i = 0; i < 64; ++i) x[i] = (x[i] - mx) * 0.5f;  // x/2 - max(x/2)

  float lo = -1.0f, hi = 0.0f;  // f(-1)>=1 (max elem alone), f(0)=0
  for (int it = 0; it < 12; ++it) {
    float tau = 0.5f * (lo + hi);
    float f = 0.0f;
#pragma unroll
    for (int i = 0; i < 64; ++i) {
      float u = fmaxf(x[i] - tau, 0.0f);
      f = fmaf(u, u, f);
    }
    f += __shfl_xor(f, 1);
    if (f >= 1.0f) lo = tau; else hi = tau;
  }
  float tau0 = 0.5f * (lo + hi);
  // exact solve on support {x > tau0}: k*tau^2 - 2*s1*tau + (s2-1) = 0
  float cnt = 0.f, s1 = 0.f, s2 = 0.f;
#pragma unroll
  for (int i = 0; i < 64; ++i) {
    bool in = x[i] > tau0;
    float xv = in ? x[i] : 0.0f;
    cnt += in ? 1.0f : 0.0f;
    s1 += xv;
    s2 = fmaf(xv, xv, s2);
  }
  cnt += __shfl_xor(cnt, 1);
  s1 += __shfl_xor(s1, 1);
  s2 += __shfl_xor(s2, 1);
  float mean = s1 / cnt;
  float ss = s2 - mean * s1;            // == k*(meansq - mean^2)
  float delta = (1.0f - ss) / cnt;
  float tau = mean - sqrtf(fmaxf(delta, 0.0f));

  unsigned short pv[64];
#pragma unroll
  for (int i = 0; i < 64; ++i) {
    float u = fmaxf(x[i] - tau, 0.0f);
    pv[i] = f2bf(u * u);
  }
  // contiguous 128B store per thread at Wq2[(m,n,t)][h*64 ...]
  uint4* o = (uint4*)(wq2 + (size_t)gv * D_ + h * 64);
#pragma unroll
  for (int j = 0; j < 8; ++j) {
    uint4 w;
    w.x = (unsigned)pv[8 * j + 0] | ((unsigned)pv[8 * j + 1] << 16);
    w.y = (unsigned)pv[8 * j + 2] | ((unsigned)pv[8 * j + 3] << 16);
    w.z = (unsigned)pv[8 * j + 4] | ((unsigned)pv[8 * j + 5] << 16);
    w.w = (unsigned)pv[8 * j + 6] | ((unsigned)pv[8 * j + 7] << 16);
    o[j] = w;
  }
}

// ---------------------------------------------------------------------------
// K2: priors = sum_d x[b,m,d] * W[m,n,d,t]  (per-m GEMM, K=128)
// Block = (n, b-tile of 64, m); C tile 64x64; mfma_f32_16x16x32_bf16.
// Epilogue: transpose C through LDS -> one contiguous 8KB slab store per
// block (layout priors[n][m][b][t]), dwordx4-coalesced.
// [R2 fix vs R1: stores were 16x 2-byte scatters at 16KB b-stride.]
// ---------------------------------------------------------------------------
#define BS_STRIDE 136
__global__ __launch_bounds__(256) void k_priors(const unsigned short* __restrict__ xb,
                                                const unsigned short* __restrict__ wq2,
                                                unsigned short* __restrict__ priors) {
  const int n = blockIdx.x, bt = blockIdx.y, m = blockIdx.z;
  const int tid = threadIdx.x;
  const int wid = tid >> 6, lane = tid & 63;
  const int row16 = lane & 15, quad = lane >> 4;
  __shared__ __align__(16) unsigned short Bs[64 * BS_STRIDE];
  __shared__ __align__(16) unsigned short Ct[64 * 72];

  const unsigned short* bsrc = wq2 + ((size_t)(m * N_ + n) * T_) * D_;  // 64x128 contiguous
  {
    int tr = tid >> 4;  // 16 rows per pass
    int c = tid & 15;   // 16B chunk within a 256B row
#pragma unroll
    for (int p = 0; p < 4; ++p) {
      int row = p * 16 + tr;
      uint4 v = *(const uint4*)(bsrc + row * D_ + c * 8);
      *(uint4*)&Bs[row * BS_STRIDE + c * 8] = v;
    }
  }
  __syncthreads();

  const int brow = bt * 64 + wid * 16 + row16;
  const unsigned short* aptr = xb + ((size_t)brow * M_ + m) * D_ + quad * 8;
  short8 afr[4];
#pragma unroll
  for (int ks = 0; ks < 4; ++ks) afr[ks] = *(const short8*)(aptr + ks * 32);

  floatx4 acc[4];
#pragma unroll
  for (int cf = 0; cf < 4; ++cf) acc[cf] = (floatx4){0.f, 0.f, 0.f, 0.f};

#pragma unroll
  for (int cf = 0; cf < 4; ++cf) {
#pragma unroll
    for (int ks = 0; ks < 4; ++ks) {
      short8 bfr = *(const short8*)&Bs[(cf * 16 + row16) * BS_STRIDE + ks * 32 + quad * 8];
      acc[cf] = __builtin_amdgcn_mfma_f32_16x16x32_bf16(afr[ks], bfr, acc[cf], 0, 0, 0);
    }
  }

  // transpose through LDS: Ct[b_local][t] bf16
#pragma unroll
  for (int cf = 0; cf < 4; ++cf) {
#pragma unroll
    for (int r = 0; r < 4; ++r) {
      Ct[(wid * 16 + quad * 4 + r) * 72 + cf * 16 + row16] = f2bf(acc[cf][r]);
    }
  }
  __syncthreads();

  {
    int row = tid >> 2, seg = tid & 3;  // 32B per thread, wave = 2KB contiguous
    uint4 w0 = *(const uint4*)&Ct[row * 72 + seg * 16];
    uint4 w1 = *(const uint4*)&Ct[row * 72 + seg * 16 + 8];
    unsigned short* dst = priors + (((size_t)n * M_ + m) * B_ + bt * 64 + row) * T_ + seg * 16;
    *(uint4*)dst = w0;
    *(uint4*)(dst + 8) = w1;
  }
}

// ---------------------------------------------------------------------------
// K3: one block per (b,n). votes = sigmoid(P @ LHn^T) [64x128] via MFMA;
// votes stay in the MFMA C-register layout (m=wid*16+quad*4+r, l=cf*16+row16).
// mean-over-m: shfl_xor(16,32) + 4x128 LDS partial; dis: in-register
// (v-mc)^2 + shfl_xor(1,2,4,8); softmax over m in wave 0; weighted sum
// parallel over 4 waves. LDS ~13KB (was 43KB), no V array.
// ---------------------------------------------------------------------------
__global__ __launch_bounds__(256) void k_route(const unsigned short* __restrict__ priors,
                                               const unsigned short* __restrict__ lhn,
                                               const float* __restrict__ thr,
                                               const float* __restrict__ gamma,
                                               const float* __restrict__ beta,
                                               float* __restrict__ out) {
  const int n = blockIdx.x, b = blockIdx.y;
  const int tid = threadIdx.x;
  const int wid = tid >> 6, lane = tid & 63;
  const int row16 = lane & 15, quad = lane >> 4;

  __shared__ __align__(16) unsigned short Ps[64 * 72];  // P [m][t] bf16 (64 data + 8 pad)
  __shared__ float mcp[4 * 128];  // per-wave column partials
  __shared__ float mc[128];
  __shared__ float disA[64];
  __shared__ float prob[64];
  __shared__ float part[4 * 64];

  {  // load P rows: priors[n][m][b][t], m-rows at stride B*T
    int mm = tid >> 2, c = tid & 3;
    const unsigned short* src = priors + (((size_t)n * M_ + mm) * B_ + b) * T_ + c * 16;
    uint4 v0 = *(const uint4*)(src);
    uint4 v1 = *(const uint4*)(src + 8);
    *(uint4*)&Ps[mm * 72 + c * 16] = v0;
    *(uint4*)&Ps[mm * 72 + c * 16 + 8] = v1;
  }
  __syncthreads();

  short8 afr[2];
#pragma unroll
  for (int ks = 0; ks < 2; ++ks)
    afr[ks] = *(const short8*)&Ps[(wid * 16 + row16) * 72 + ks * 32 + quad * 8];

  floatx4 acc[8];
#pragma unroll
  for (int cf = 0; cf < 8; ++cf) acc[cf] = (floatx4){0.f, 0.f, 0.f, 0.f};

#pragma unroll
  for (int cf = 0; cf < 8; ++cf) {
#pragma unroll
    for (int ks = 0; ks < 2; ++ks) {
      short8 bfr = *(const short8*)(lhn + (cf * 16 + row16) * T_ + ks * 32 + quad * 8);
      acc[cf] = __builtin_amdgcn_mfma_f32_16x16x32_bf16(afr[ks], bfr, acc[cf], 0, 0, 0);
    }
  }

  // sigmoid in registers: v[cf][r] for m = wid*16+quad*4+r, l = cf*16+row16
  float v[8][4];
#pragma unroll
  for (int cf = 0; cf < 8; ++cf)
#pragma unroll
    for (int r = 0; r < 4; ++r) v[cf][r] = 1.0f / (1.0f + __expf(-acc[cf][r]));

  // per-wave column sums over this wave's 16 m's -> mcp[wid][l]
#pragma unroll
  for (int cf = 0; cf < 8; ++cf) {
    float s = v[cf][0] + v[cf][1] + v[cf][2] + v[cf][3];
    s += __shfl_xor(s, 16);
    s += __shfl_xor(s, 32);
    if (quad == 0) mcp[wid * 128 + cf * 16 + row16] = s;
  }
  __syncthreads();

  if (tid < 128)
    mc[tid] = (mcp[tid] + mcp[128 + tid] + mcp[256 + tid] + mcp[384 + tid]) * (1.0f / 64.0f);
  __syncthreads();

  // dis[m] = mean_l (v - mc)^2, in registers + shfl over row16 bits
  float mcv[8];
#pragma unroll
  for (int cf = 0; cf < 8; ++cf) mcv[cf] = mc[cf * 16 + row16];
  float d[4];
#pragma unroll
  for (int r = 0; r < 4; ++r) {
    float s = 0.f;
#pragma unroll
    for (int cf = 0; cf < 8; ++cf) {
      float df = v[cf][r] - mcv[cf];
      s = fmaf(df, df, s);
    }
    d[r] = s;
  }
#pragma unroll
  for (int off = 1; off <= 8; off <<= 1) {
#pragma unroll
    for (int r = 0; r < 4; ++r) d[r] += __shfl_xor(d[r], off);
  }
  if (row16 == 0) {
#pragma unroll
    for (int r = 0; r < 4; ++r) disA[wid * 16 + quad * 4 + r] = d[r] * (1.0f / 128.0f);
  }
  __syncthreads();

  if (tid < 64) {  // softmax over m (wave 0, m = tid)
    float dis = disA[tid];
    float th = thr[tid * N_ + n];
    float w = fmaxf(th * th - dis, 0.0f);
    float mxw = w;
#pragma unroll
    for (int off = 1; off <= 32; off <<= 1) mxw = fmaxf(mxw, __shfl_xor(mxw, off));
    float e = __expf(w - mxw);
    float s = e;
#pragma unroll
    for (int off = 1; off <= 32; off <<= 1) s += __shfl_xor(s, off);
    prob[tid] = e / s;
  }
  __syncthreads();

  {  // weighted sum partials: wave wid handles m in [wid*16, wid*16+16)
    float s = 0.f;
#pragma unroll
    for (int j = 0; j < 16; ++j) {
      int mm = wid * 16 + j;
      s = fmaf(prob[mm], bf2f(Ps[mm * 72 + lane]), s);
    }
    part[wid * 64 + lane] = s;
  }
  __syncthreads();

  if (tid < 64) {  // final sum + LayerNorm over T (t = tid)
    float s = part[tid] + part[64 + tid] + part[128 + tid] + part[192 + tid];
    float mu = s;
#pragma unroll
    for (int off = 1; off <= 32; off <<= 1) mu += __shfl_xor(mu, off);
    mu *= (1.0f / 64.0f);
    float df = s - mu;
    float var = df * df;
#pragma unroll
    for (int off = 1; off <= 32; off <<= 1) var += __shfl_xor(var, off);
    var *= (1.0f / 64.0f);
    float o = df * rsqrtf(var + 1e-5f) * gamma[tid] + beta[tid];
    out[((size_t)b * N_ + n) * T_ + tid] = o;
  }
}

// ---------------------------------------------------------------------------
// Workspace layout (bytes):
//   Wq2    [M][N][T][D] bf16 : off 0,           33,554,432
//   priors [N][M][B][T] bf16 : off 33,554,432,  67,108,864   (layout changed R2)
//   xb     [B][M][D]    bf16 : off 100,663,296,  4,194,304
//   LHn    [L][T]       bf16 : off 104,857,600,     16,384
// total ~100 MB
// ---------------------------------------------------------------------------
extern "C" void kernel_launch(void* const* d_in, const int* in_sizes, int n_in,
                              void* d_out, int out_size, void* d_ws, size_t ws_size,
                              hipStream_t stream) {
  const float* x = (const float*)d_in[0];
  const float* rw = (const float*)d_in[1];
  const float* thr = (const float*)d_in[2];
  const float* leaves = (const float*)d_in[3];
  const float* gamma = (const float*)d_in[4];
  const float* beta = (const float*)d_in[5];
  float* out = (float*)d_out;

  char* ws = (char*)d_ws;
  unsigned short* wq2 = (unsigned short*)(ws);
  unsigned short* priors = (unsigned short*)(ws + 33554432);
  unsigned short* xb = (unsigned short*)(ws + 33554432 + 67108864);
  unsigned short* lhn = (unsigned short*)(ws + 33554432 + 67108864 + 4194304);

  hipLaunchKernelGGL(k_prep, dim3(2049), dim3(256), 0, stream, x, leaves, xb, lhn);
  hipLaunchKernelGGL(k_entmax, dim3(1024), dim3(256), 0, stream, rw, wq2);
  hipLaunchKernelGGL(k_priors, dim3(32, 4, 64), dim3(256), 0, stream, xb, wq2, priors);
  hipLaunchKernelGGL(k_route, dim3(32, 256), dim3(256), 0, stream, priors, lhn, thr, gamma, beta, out);
}